// Round 6
// baseline (345.010 us; speedup 1.0000x reference)
//
#include <hip/hip_runtime.h>
#include <hip/hip_bf16.h>
#include <hip/hip_cooperative_groups.h>

namespace cg = cooperative_groups;

// ---------------------------------------------------------------------------
// LinearSelfAttention: out = Q@state + tril(Q Q^T,-1)@V ; new_state = state + Q^T V
// B=4 T=2048 nh=8 N=64 D=128.  R6 = R5 with the bit_cast compile fix:
// cooperative fused kernel (grid 512 = 2 blocks/CU guaranteed), runtime
// fallback to the verified R3 3-kernel path if cooperative launch fails.
//   phase1:  S_c[i][d] = sum_{t in chunk} Q[t][i] V[t][d]   (bf16 ws1, [i][d])
//   prefix:  P_c = state + sum_{c'<c} S_c'  (bf16 ws2); new_state fp32
//   phase2:  O_c = Q_c @ P_c + tril(Q_c Q_c^T,-1) @ V_c
// MFMA = f32_16x16x32_bf16.  C/D: col=lane&15, row=quad*4+reg (m89-verified).
// A frag: A[m=lane&15][k=quad*8+j]; B frags read from B^T stored [n][k].
// Packed bf16 cvt (v_cvt_pk_bf16_f32) for all staging/prefix conversions.
// ---------------------------------------------------------------------------

using floatx4 = __attribute__((ext_vector_type(4))) float;
using float4v = __attribute__((ext_vector_type(4))) float;
using float2v = __attribute__((ext_vector_type(2))) float;
using shortx8 = __attribute__((ext_vector_type(8))) short;
using shortx4 = __attribute__((ext_vector_type(4))) short;
using uint2v  = __attribute__((ext_vector_type(2))) unsigned int;

#define MFMA16(a, b, c) __builtin_amdgcn_mfma_f32_16x16x32_bf16((a), (b), (c), 0, 0, 0)

__device__ __forceinline__ unsigned short f2bf(float f) {
  unsigned int u = __builtin_bit_cast(unsigned int, f);
  u += 0x7FFFu + ((u >> 16) & 1u);   // RNE (scalar path, used for Ss stores)
  return (unsigned short)(u >> 16);
}
__device__ __forceinline__ float bf2f(unsigned short h) {
  unsigned int u = ((unsigned int)h) << 16;
  return __builtin_bit_cast(float, u);
}
// packed f32x2 -> bf16x2 via HW v_cvt_pk_bf16_f32 (memcpy: bf162 isn't
// trivially copyable on this ROCm, bit_cast rejected -- memcpy is free)
__device__ __forceinline__ unsigned int pack2(float a, float b) {
  __hip_bfloat162 h = __float22bfloat162_rn(float2{a, b});
  unsigned int u;
  __builtin_memcpy(&u, &h, 4);
  return u;
}
__device__ __forceinline__ shortx8 lds8(const unsigned short* p) {
  shortx4 a = *(const shortx4*)p;
  shortx4 b = *(const shortx4*)(p + 4);
  return __builtin_shufflevector(a, b, 0, 1, 2, 3, 4, 5, 6, 7);
}

// job -> (b,n,c): jobs sharing (b,c) differ by 8 -> same XCD (round-robin).
#define DECODE_JOB(job)                                 \
  const int n = ((job) >> 3) & 7;                       \
  const int bc = ((job) >> 6) * 8 + ((job) & 7);        \
  const int b = bc >> 5, c = bc & 31

// ===========================================================================
// Shared phase bodies (used by both fused and standalone kernels)
// ===========================================================================
__device__ __forceinline__ void phase1_body(int job, int tid,
                                            const float* __restrict__ Q,
                                            const float* __restrict__ V,
                                            unsigned short* __restrict__ ws1,
                                            unsigned short* Qt,   // [i][t] 64x68
                                            unsigned short* Vt) { // [d][t] 128x68
  DECODE_JOB(job);
  const int wave = tid >> 6, lane = tid & 63;
  const int col = lane & 15, quad = lane >> 4;
  const float* qbase = Q + (((size_t)(b * 2048 + c * 64) * 8 + n) * 64);
  const float* vbase = V + ((size_t)(b * 2048 + c * 64) * 128);

  // convert-transpose staging: coalesced dword loads, paired-t u32 writes
#pragma unroll
  for (int it = 0; it < 8; ++it) {      // Q: 64 i x 32 t-pairs
    int j = tid + it * 256;
    int i = j & 63, p = j >> 6;
    float q0 = qbase[(2 * p) * 512 + i];
    float q1 = qbase[(2 * p + 1) * 512 + i];
    *(unsigned int*)&Qt[i * 68 + 2 * p] = pack2(q0, q1);
  }
#pragma unroll
  for (int it = 0; it < 16; ++it) {     // V: 128 d x 32 t-pairs
    int j = tid + it * 256;
    int d = j & 127, p = j >> 7;
    float v0 = vbase[(2 * p) * 128 + d];
    float v1 = vbase[(2 * p + 1) * 128 + d];
    *(unsigned int*)&Vt[d * 68 + 2 * p] = pack2(v0, v1);
  }
  __syncthreads();

  // D[m=i][n=d]: wave -> d-tiles {2w,2w+1}, all 4 i-tiles.  K=64 over t.
  floatx4 acc[4][2];
#pragma unroll
  for (int ti = 0; ti < 4; ++ti)
#pragma unroll
    for (int dj = 0; dj < 2; ++dj) acc[ti][dj] = (floatx4){0.f, 0.f, 0.f, 0.f};

#pragma unroll
  for (int s = 0; s < 2; ++s) {
    const int koff = s * 32 + quad * 8;
    shortx8 bv[2];
#pragma unroll
    for (int dj = 0; dj < 2; ++dj)
      bv[dj] = lds8(&Vt[((wave * 2 + dj) * 16 + col) * 68 + koff]);
#pragma unroll
    for (int ti = 0; ti < 4; ++ti) {
      shortx8 aq = lds8(&Qt[(ti * 16 + col) * 68 + koff]);
#pragma unroll
      for (int dj = 0; dj < 2; ++dj) acc[ti][dj] = MFMA16(aq, bv[dj], acc[ti][dj]);
    }
  }

  unsigned short* wbase = ws1 + (size_t)((b * 8 + n) * 32 + c) * 8192;
#pragma unroll
  for (int ti = 0; ti < 4; ++ti)
#pragma unroll
    for (int dj = 0; dj < 2; ++dj)
#pragma unroll
      for (int r = 0; r < 4; ++r) {
        int i = ti * 16 + quad * 4 + r;
        int d = (wave * 2 + dj) * 16 + col;
        wbase[i * 128 + d] = f2bf(acc[ti][dj][r]);
      }
}

__device__ __forceinline__ void prefix_body(int t,   // global thread 0..131071
                                            const float* __restrict__ state,
                                            const unsigned int* __restrict__ w1base,
                                            unsigned int* __restrict__ w2base,
                                            float* __restrict__ new_state) {
  int bn = t >> 12;
  int e2 = t & 4095;                         // u32 pair index within [i][d]
  float2v st = *(const float2v*)(state + (size_t)bn * 8192 + 2 * e2);
  float run0 = st.x, run1 = st.y;
  const unsigned int* w1 = w1base + (size_t)bn * 131072 + e2;
  unsigned int* w2 = w2base + (size_t)bn * 131072 + e2;
#pragma unroll
  for (int g = 0; g < 32; ++g) {
    w2[g * 4096] = pack2(run0, run1);
    unsigned int s = w1[g * 4096];
    run0 += bf2f((unsigned short)(s & 0xFFFFu));
    run1 += bf2f((unsigned short)(s >> 16));
  }
  float2v ns; ns.x = run0; ns.y = run1;
  *(float2v*)(new_state + (size_t)bn * 8192 + 2 * e2) = ns;
}

__device__ __forceinline__ void phase2_body(int job, int tid,
                                            const float* __restrict__ Q,
                                            const float* __restrict__ V,
                                            const unsigned short* __restrict__ ws2,
                                            float* __restrict__ out,
                                            unsigned short* Qs,   // [t][k] 64x72
                                            unsigned short* Vt,   // [d][u] 128x68
                                            unsigned short* Ss,   // [t][u] 64x72
                                            unsigned short* Pt) { // [d][i] 128x68
  DECODE_JOB(job);
  const int wave = tid >> 6, lane = tid & 63;
  const int col = lane & 15, quad = lane >> 4;

  // stage Pt: ws2 [i][d] -> Pt[d][i]
  {
    const unsigned int* pb32 =
        (const unsigned int*)(ws2 + (size_t)((b * 8 + n) * 32 + c) * 8192);
#pragma unroll
    for (int it = 0; it < 16; ++it) {
      int j = tid + it * 256;
      int d2 = j & 63, i = j >> 6;
      unsigned int u = pb32[i * 64 + d2];   // coalesced: d2 fastest
      Pt[(2 * d2) * 68 + i] = (unsigned short)(u & 0xFFFFu);
      Pt[(2 * d2 + 1) * 68 + i] = (unsigned short)(u >> 16);
    }
  }
  const float* qbase = Q + (((size_t)(b * 2048 + c * 64) * 8 + n) * 64);
  const float* vbase = V + ((size_t)(b * 2048 + c * 64) * 128);
  float* obase = out + (((size_t)(b * 2048 + c * 64) * 8 + n) * 128);

#pragma unroll
  for (int it = 0; it < 4; ++it) {         // Qs [t][k]
    int l = tid + it * 256;
    int t = l >> 4, k4 = (l & 15) * 4;
    float4v q = *(const float4v*)(qbase + (size_t)t * 512 + k4);
    uint2v u;
    u.x = pack2(q.x, q.y);
    u.y = pack2(q.z, q.w);
    *(uint2v*)&Qs[t * 72 + k4] = u;
  }
#pragma unroll
  for (int it = 0; it < 16; ++it) {        // Vt [d][u] convert-transpose
    int j = tid + it * 256;
    int d = j & 127, p = j >> 7;
    float v0 = vbase[(size_t)(2 * p) * 128 + d];
    float v1 = vbase[(size_t)(2 * p + 1) * 128 + d];
    *(unsigned int*)&Vt[d * 68 + 2 * p] = pack2(v0, v1);
  }
  __syncthreads();   // B1: staging visible

  // scores: S[t][u] = Q Q^T, strict-causal mask -> Ss
  {
    int w = 0;
    for (int ti = 0; ti < 4; ++ti)
      for (int ui = 0; ui <= (ti | 1); ++ui, ++w) {
        if ((w & 3) != wave) continue;
        if (ui > ti) {                     // masked tile read by K-loop: zero
#pragma unroll
          for (int r = 0; r < 4; ++r)
            Ss[(ti * 16 + quad * 4 + r) * 72 + ui * 16 + col] = 0;
        } else {
          floatx4 sc = (floatx4){0.f, 0.f, 0.f, 0.f};
#pragma unroll
          for (int s = 0; s < 2; ++s) {
            shortx8 at = *(const shortx8*)&Qs[(ti * 16 + col) * 72 + s * 32 + quad * 8];
            shortx8 au = *(const shortx8*)&Qs[(ui * 16 + col) * 72 + s * 32 + quad * 8];
            sc = MFMA16(at, au, sc);
          }
#pragma unroll
          for (int r = 0; r < 4; ++r) {
            int t = ti * 16 + quad * 4 + r, u = ui * 16 + col;
            Ss[t * 72 + u] = (u < t) ? f2bf(sc[r]) : (unsigned short)0;
          }
        }
      }
  }
  __syncthreads();   // B2: Ss visible

  // O accum: wave -> d-tiles {2w,2w+1}, all 4 t-tiles
  floatx4 acc[4][2];
#pragma unroll
  for (int ti = 0; ti < 4; ++ti)
#pragma unroll
    for (int dj = 0; dj < 2; ++dj) acc[ti][dj] = (floatx4){0.f, 0.f, 0.f, 0.f};

  // Q @ P (K=64 over i)
#pragma unroll
  for (int s = 0; s < 2; ++s) {
    const int koff = s * 32 + quad * 8;
    shortx8 bp[2];
#pragma unroll
    for (int dj = 0; dj < 2; ++dj)
      bp[dj] = lds8(&Pt[((wave * 2 + dj) * 16 + col) * 68 + koff]);
#pragma unroll
    for (int ti = 0; ti < 4; ++ti) {
      shortx8 aq = *(const shortx8*)&Qs[(ti * 16 + col) * 72 + koff];
#pragma unroll
      for (int dj = 0; dj < 2; ++dj) acc[ti][dj] = MFMA16(aq, bp[dj], acc[ti][dj]);
    }
  }
  // S @ V (skip K-steps entirely above the diagonal)
#pragma unroll
  for (int s = 0; s < 2; ++s) {
    const int koff = s * 32 + quad * 8;
    shortx8 bv[2];
#pragma unroll
    for (int dj = 0; dj < 2; ++dj)
      bv[dj] = lds8(&Vt[((wave * 2 + dj) * 16 + col) * 68 + koff]);
    for (int ti = (s == 0 ? 0 : 2); ti < 4; ++ti) {
      shortx8 as = *(const shortx8*)&Ss[(ti * 16 + col) * 72 + koff];
#pragma unroll
      for (int dj = 0; dj < 2; ++dj) acc[ti][dj] = MFMA16(as, bv[dj], acc[ti][dj]);
    }
  }
  // store O chunk
#pragma unroll
  for (int ti = 0; ti < 4; ++ti)
#pragma unroll
    for (int dj = 0; dj < 2; ++dj)
#pragma unroll
      for (int r = 0; r < 4; ++r) {
        int t = ti * 16 + quad * 4 + r;
        int d = (wave * 2 + dj) * 16 + col;
        obase[(size_t)t * 1024 + d] = acc[ti][dj][r];
      }
}

// ===========================================================================
// Fused cooperative kernel: grid 512 (2 blocks/CU), 2 jobs/block per phase.
// ===========================================================================
__global__ __launch_bounds__(256, 2) void k_fused(
    const float* __restrict__ Q, const float* __restrict__ V,
    const float* __restrict__ state, unsigned short* __restrict__ ws1,
    unsigned short* __restrict__ ws2, float* __restrict__ out,
    float* __restrict__ new_state) {
  __shared__ __align__(16) unsigned short smem[26624];   // 53,248 B
  cg::grid_group grid = cg::this_grid();

  const int bid = blockIdx.x;
  const int tid = threadIdx.x;

  // phase 1: jobs bid, bid+512
  phase1_body(bid, tid, Q, V, ws1, smem, smem + 4352);
  __syncthreads();   // job0 LDS reads done before restage
  phase1_body(bid + 512, tid, Q, V, ws1, smem, smem + 4352);

  __threadfence();
  grid.sync();

  // prefix: 512*256 = 131072 threads exactly
  prefix_body(bid * 256 + tid, state, (const unsigned int*)ws1,
              (unsigned int*)ws2, new_state);

  __threadfence();
  grid.sync();

  // phase 2: jobs bid, bid+512
  phase2_body(bid, tid, Q, V, ws2, out,
              smem, smem + 4608, smem + 13312, smem + 17920);
  __syncthreads();   // job0 LDS reads done before restage
  phase2_body(bid + 512, tid, Q, V, ws2, out,
              smem, smem + 4608, smem + 13312, smem + 17920);
}

// ===========================================================================
// Fallback standalone kernels (verified R3 structure)
// ===========================================================================
__global__ __launch_bounds__(256) void k_phase1(const float* __restrict__ Q,
                                                const float* __restrict__ V,
                                                unsigned short* __restrict__ ws1) {
  __shared__ __align__(16) unsigned short smem[13056];   // 64*68 + 128*68
  phase1_body(blockIdx.x, threadIdx.x, Q, V, ws1, smem, smem + 4352);
}

__global__ __launch_bounds__(256) void k_prefix(const float* __restrict__ state,
                                                const unsigned int* __restrict__ ws1,
                                                unsigned int* __restrict__ ws2,
                                                float* __restrict__ new_state) {
  prefix_body(blockIdx.x * 256 + threadIdx.x, state, ws1, ws2, new_state);
}

__global__ __launch_bounds__(256) void k_phase2(const float* __restrict__ Q,
                                                const float* __restrict__ V,
                                                const unsigned short* __restrict__ ws2,
                                                float* __restrict__ out) {
  __shared__ __align__(16) unsigned short smem[26624];
  phase2_body(blockIdx.x, threadIdx.x, Q, V, ws2, out,
              smem, smem + 4608, smem + 13312, smem + 17920);
}

// ---------------------------------------------------------------------------
extern "C" void kernel_launch(void* const* d_in, const int* in_sizes, int n_in,
                              void* d_out, int out_size, void* d_ws, size_t ws_size,
                              hipStream_t stream) {
  (void)in_sizes; (void)n_in; (void)out_size; (void)ws_size;
  const float* Q     = (const float*)d_in[0];
  const float* V     = (const float*)d_in[1];
  const float* state = (const float*)d_in[2];
  float* out        = (float*)d_out;
  float* new_state  = out + (size_t)4 * 2048 * 8 * 128;
  unsigned short* ws1 = (unsigned short*)d_ws;             // 16.8 MB bf16 [bn][32][i][d]
  unsigned short* ws2 = ws1 + (size_t)32 * 32 * 8192;      // 16.8 MB bf16

  void* args[] = {(void*)&Q, (void*)&V, (void*)&state, (void*)&ws1,
                  (void*)&ws2, (void*)&out, (void*)&new_state};
  hipError_t err = hipLaunchCooperativeKernel((void*)k_fused, dim3(512), dim3(256),
                                              args, 0, stream);
  if (err != hipSuccess) {
    // Fallback: verified 3-kernel path (same math, same buffers).
    k_phase1<<<1024, 256, 0, stream>>>(Q, V, ws1);
    k_prefix<<<512, 256, 0, stream>>>(state, (const unsigned int*)ws1,
                                      (unsigned int*)ws2, new_state);
    k_phase2<<<1024, 256, 0, stream>>>(Q, V, ws2, out);
  }
}

// Round 7
// 103.547 us; speedup vs baseline: 3.3319x; 3.3319x over previous
//
#include <hip/hip_runtime.h>
#include <hip/hip_bf16.h>

// ---------------------------------------------------------------------------
// LinearSelfAttention: out = Q@state + tril(Q Q^T,-1)@V ; new_state = state + Q^T V
// B=4 T=2048 nh=8 N=64 D=128.  R7: back to 3 plain kernels (cooperative fusion
// measured pathological in R6: grid.sync cost ~200us).  Changes vs R3:
//  - ws1/ws2 stored in MFMA-register-PERMUTED order: phase1 epilogue becomes
//    4x uint4 coalesced stores (was 32 scalar u16 stores); prefix cumsum is
//    permutation-invariant; phase2 Pt staging decodes the permutation with
//    coalesced reads + aligned u32 LDS writes.
//  - Pt ld 68->72: B-fragment read is one ds_read_b128 (16B-aligned rows).
//  - phase2 out epilogue: LDS bounce -> 8x dwordx4 coalesced stores
//    (was 32 scalar f32 stores) for the 33.6MB out tensor.
// MFMA = f32_16x16x32_bf16.  C/D: col=lane&15, row=quad*4+reg (m89-verified).
// A frag: A[m=lane&15][k=quad*8+j]; B frags read from B^T stored [n][k].
//
// Permuted chunk layout (u32 units, 4096/chunk): idx = k*1024 + tid*4 + e,
// where k=ti (0..3), e = dj*2 + rp;  u32 = pack2(acc[ti][dj][2rp], [2rp+1]).
// Decode: tid0=(idx>>2)&255, e=idx&3; quad0=(tid0>>4)&3, col0=tid0&15,
// wave0=tid0>>6; i0 = k*16+quad0*4+(e&1)*2 (+0/+1), d=((wave0*2)+(e>>1))*16+col0.
// ---------------------------------------------------------------------------

using floatx4 = __attribute__((ext_vector_type(4))) float;
using float4v = __attribute__((ext_vector_type(4))) float;
using shortx8 = __attribute__((ext_vector_type(8))) short;
using shortx4 = __attribute__((ext_vector_type(4))) short;
using uint2v  = __attribute__((ext_vector_type(2))) unsigned int;
using uint4v  = __attribute__((ext_vector_type(4))) unsigned int;

#define MFMA16(a, b, c) __builtin_amdgcn_mfma_f32_16x16x32_bf16((a), (b), (c), 0, 0, 0)

__device__ __forceinline__ unsigned short f2bf(float f) {
  unsigned int u = __builtin_bit_cast(unsigned int, f);
  u += 0x7FFFu + ((u >> 16) & 1u);   // RNE (scalar path)
  return (unsigned short)(u >> 16);
}
__device__ __forceinline__ float bf2f(unsigned short h) {
  unsigned int u = ((unsigned int)h) << 16;
  return __builtin_bit_cast(float, u);
}
// packed f32x2 -> bf16x2 via HW v_cvt_pk_bf16_f32
__device__ __forceinline__ unsigned int pack2(float a, float b) {
  __hip_bfloat162 h = __float22bfloat162_rn(float2{a, b});
  unsigned int u;
  __builtin_memcpy(&u, &h, 4);
  return u;
}
__device__ __forceinline__ shortx8 lds8(const unsigned short* p) {
  shortx4 a = *(const shortx4*)p;
  shortx4 b = *(const shortx4*)(p + 4);
  return __builtin_shufflevector(a, b, 0, 1, 2, 3, 4, 5, 6, 7);
}

// job -> (b,n,c): jobs sharing (b,c) differ by 8 -> same XCD (round-robin).
#define DECODE_JOB(job)                                 \
  const int n = ((job) >> 3) & 7;                       \
  const int bc = ((job) >> 6) * 8 + ((job) & 7);        \
  const int b = bc >> 5, c = bc & 31

// ---------------------------------------------------------------------------
// Phase 1: S_c = Q_c^T V_c -> ws1 (bf16, permuted).  grid 1024, block 256.
// ---------------------------------------------------------------------------
__global__ __launch_bounds__(256) void k_phase1(const float* __restrict__ Q,
                                                const float* __restrict__ V,
                                                unsigned int* __restrict__ ws1) {
  __shared__ __align__(16) unsigned short Qt[64 * 68];   // [i][t]
  __shared__ __align__(16) unsigned short Vt[128 * 68];  // [d][t]

  DECODE_JOB(blockIdx.x);
  const int tid = threadIdx.x;
  const int wave = tid >> 6, lane = tid & 63;
  const int col = lane & 15, quad = lane >> 4;
  const float* qbase = Q + (((size_t)(b * 2048 + c * 64) * 8 + n) * 64);
  const float* vbase = V + ((size_t)(b * 2048 + c * 64) * 128);

  // convert-transpose staging: coalesced dword loads, paired-t u32 writes
#pragma unroll
  for (int it = 0; it < 8; ++it) {      // Q: 64 i x 32 t-pairs
    int j = tid + it * 256;
    int i = j & 63, p = j >> 6;
    float q0 = qbase[(2 * p) * 512 + i];
    float q1 = qbase[(2 * p + 1) * 512 + i];
    *(unsigned int*)&Qt[i * 68 + 2 * p] = pack2(q0, q1);
  }
#pragma unroll
  for (int it = 0; it < 16; ++it) {     // V: 128 d x 32 t-pairs
    int j = tid + it * 256;
    int d = j & 127, p = j >> 7;
    float v0 = vbase[(2 * p) * 128 + d];
    float v1 = vbase[(2 * p + 1) * 128 + d];
    *(unsigned int*)&Vt[d * 68 + 2 * p] = pack2(v0, v1);
  }
  __syncthreads();

  // D[m=i][n=d]: wave -> d-tiles {2w,2w+1}, all 4 i-tiles.  K=64 over t.
  floatx4 acc[4][2];
#pragma unroll
  for (int ti = 0; ti < 4; ++ti)
#pragma unroll
    for (int dj = 0; dj < 2; ++dj) acc[ti][dj] = (floatx4){0.f, 0.f, 0.f, 0.f};

#pragma unroll
  for (int s = 0; s < 2; ++s) {
    const int koff = s * 32 + quad * 8;
    shortx8 bv[2];
#pragma unroll
    for (int dj = 0; dj < 2; ++dj)
      bv[dj] = lds8(&Vt[((wave * 2 + dj) * 16 + col) * 68 + koff]);
#pragma unroll
    for (int ti = 0; ti < 4; ++ti) {
      shortx8 aq = lds8(&Qt[(ti * 16 + col) * 68 + koff]);
#pragma unroll
      for (int dj = 0; dj < 2; ++dj) acc[ti][dj] = MFMA16(aq, bv[dj], acc[ti][dj]);
    }
  }

  // permuted epilogue: 4 x uint4, fully coalesced (1 KB/wave/instr)
  unsigned int* wbase = ws1 + (size_t)((b * 8 + n) * 32 + c) * 4096;
#pragma unroll
  for (int k = 0; k < 4; ++k) {
    uint4v X;
    X.x = pack2(acc[k][0][0], acc[k][0][1]);   // e=0: dj=0 rp=0
    X.y = pack2(acc[k][0][2], acc[k][0][3]);   // e=1: dj=0 rp=1
    X.z = pack2(acc[k][1][0], acc[k][1][1]);   // e=2: dj=1 rp=0
    X.w = pack2(acc[k][1][2], acc[k][1][3]);   // e=3: dj=1 rp=1
    *(uint4v*)(wbase + k * 1024 + tid * 4) = X;
  }
}

// ---------------------------------------------------------------------------
// Prefix over 32 chunks in permuted space (cumsum is permutation-invariant).
// grid 512, block 256.  ws1/ws2 accesses coalesced; state/new_state scalar x2.
// ---------------------------------------------------------------------------
__global__ __launch_bounds__(256) void k_prefix(const float* __restrict__ state,
                                                const unsigned int* __restrict__ ws1,
                                                unsigned int* __restrict__ ws2,
                                                float* __restrict__ new_state) {
  int t = blockIdx.x * 256 + threadIdx.x;    // 0..131071
  int bn = t >> 12;
  int p = t & 4095;                           // permuted u32 position
  // decode permutation -> (i0, i0+1, d)
  int k = p >> 10, tid0 = (p >> 2) & 255, e = p & 3;
  int i0 = k * 16 + ((tid0 >> 4) & 3) * 4 + (e & 1) * 2;
  int d  = ((tid0 >> 6) * 2 + (e >> 1)) * 16 + (tid0 & 15);
  const float* sbase = state + (size_t)bn * 8192;
  float run0 = sbase[i0 * 128 + d];
  float run1 = sbase[(i0 + 1) * 128 + d];
  const unsigned int* w1 = ws1 + (size_t)bn * 131072 + p;
  unsigned int* w2 = ws2 + (size_t)bn * 131072 + p;
#pragma unroll
  for (int g = 0; g < 32; ++g) {
    w2[g * 4096] = pack2(run0, run1);
    unsigned int s = w1[g * 4096];
    run0 += bf2f((unsigned short)(s & 0xFFFFu));
    run1 += bf2f((unsigned short)(s >> 16));
  }
  float* nbase = new_state + (size_t)bn * 8192;
  nbase[i0 * 128 + d] = run0;
  nbase[(i0 + 1) * 128 + d] = run1;
}

// ---------------------------------------------------------------------------
// Phase 2: one 64-chunk per block:  O = Q_c @ P_c + tril(Q_c Q_c^T,-1) @ V_c.
// grid 1024, block 256.  LDS 54,272 B -> 3 blocks/CU.
// smem layout (u16 units): Qs[0,4608) Vt[4608,13312) Ss[13312,17920)
//                          Pt[17920,27136)   (Pt ld=72 -> b128 frag reads)
// Epilogue bounces O through LDS (aliases whole smem as fp32 64x132).
// ---------------------------------------------------------------------------
__global__ __launch_bounds__(256) void k_phase2(const float* __restrict__ Q,
                                                const float* __restrict__ V,
                                                const unsigned int* __restrict__ ws2,
                                                float* __restrict__ out) {
  __shared__ __align__(16) unsigned short smem[27136];
  unsigned short* Qs = smem;            // [t][k] 64 x 72
  unsigned short* Vt = smem + 4608;     // [d][u] 128 x 68
  unsigned short* Ss = smem + 13312;    // [t][u] 64 x 72
  unsigned short* Pt = smem + 17920;    // [d][i] 128 x 72

  DECODE_JOB(blockIdx.x);
  const int tid = threadIdx.x;
  const int wave = tid >> 6, lane = tid & 63;
  const int col = lane & 15, quad = lane >> 4;

  // stage Pt from permuted ws2: coalesced u32 reads, aligned u32 LDS writes
  {
    const unsigned int* pb32 = ws2 + (size_t)((b * 8 + n) * 32 + c) * 4096;
#pragma unroll
    for (int it = 0; it < 16; ++it) {
      int j = tid + it * 256;
      int k = j >> 10, tid0 = (j >> 2) & 255, e = j & 3;
      int i0 = k * 16 + ((tid0 >> 4) & 3) * 4 + (e & 1) * 2;
      int d  = ((tid0 >> 6) * 2 + (e >> 1)) * 16 + (tid0 & 15);
      unsigned int u = pb32[j];
      *(unsigned int*)&Pt[d * 72 + i0] = u;   // (i0, i0+1) pair, 4B-aligned
    }
  }
  const float* qbase = Q + (((size_t)(b * 2048 + c * 64) * 8 + n) * 64);
  const float* vbase = V + ((size_t)(b * 2048 + c * 64) * 128);
  float* obase = out + (((size_t)(b * 2048 + c * 64) * 8 + n) * 128);

#pragma unroll
  for (int it = 0; it < 4; ++it) {         // Qs [t][k], b64 writes
    int l = tid + it * 256;
    int t = l >> 4, k4 = (l & 15) * 4;
    float4v q = *(const float4v*)(qbase + (size_t)t * 512 + k4);
    uint2v u;
    u.x = pack2(q.x, q.y);
    u.y = pack2(q.z, q.w);
    *(uint2v*)&Qs[t * 72 + k4] = u;
  }
#pragma unroll
  for (int it = 0; it < 16; ++it) {        // Vt [d][u] convert-transpose
    int j = tid + it * 256;
    int d = j & 127, p = j >> 7;
    float v0 = vbase[(size_t)(2 * p) * 128 + d];
    float v1 = vbase[(size_t)(2 * p + 1) * 128 + d];
    *(unsigned int*)&Vt[d * 68 + 2 * p] = pack2(v0, v1);
  }
  __syncthreads();   // B1: staging visible

  // scores: S[t][u] = Q Q^T, strict-causal mask -> Ss
  {
    int w = 0;
    for (int ti = 0; ti < 4; ++ti)
      for (int ui = 0; ui <= (ti | 1); ++ui, ++w) {
        if ((w & 3) != wave) continue;
        if (ui > ti) {                     // masked tile read by K-loop: zero
#pragma unroll
          for (int r = 0; r < 4; ++r)
            Ss[(ti * 16 + quad * 4 + r) * 72 + ui * 16 + col] = 0;
        } else {
          floatx4 sc = (floatx4){0.f, 0.f, 0.f, 0.f};
#pragma unroll
          for (int s = 0; s < 2; ++s) {
            shortx8 at = *(const shortx8*)&Qs[(ti * 16 + col) * 72 + s * 32 + quad * 8];
            shortx8 au = *(const shortx8*)&Qs[(ui * 16 + col) * 72 + s * 32 + quad * 8];
            sc = MFMA16(at, au, sc);
          }
#pragma unroll
          for (int r = 0; r < 4; ++r) {
            int t = ti * 16 + quad * 4 + r, u = ui * 16 + col;
            Ss[t * 72 + u] = (u < t) ? f2bf(sc[r]) : (unsigned short)0;
          }
        }
      }
  }
  __syncthreads();   // B2: Ss visible

  // O accum: wave -> d-tiles {2w,2w+1}, all 4 t-tiles
  floatx4 acc[4][2];
#pragma unroll
  for (int ti = 0; ti < 4; ++ti)
#pragma unroll
    for (int dj = 0; dj < 2; ++dj) acc[ti][dj] = (floatx4){0.f, 0.f, 0.f, 0.f};

  // Q @ P (K=64 over i); Pt rows are 16B-aligned -> single b128 frag read
#pragma unroll
  for (int s = 0; s < 2; ++s) {
    const int koff = s * 32 + quad * 8;
    shortx8 bp[2];
#pragma unroll
    for (int dj = 0; dj < 2; ++dj)
      bp[dj] = *(const shortx8*)&Pt[((wave * 2 + dj) * 16 + col) * 72 + koff];
#pragma unroll
    for (int ti = 0; ti < 4; ++ti) {
      shortx8 aq = *(const shortx8*)&Qs[(ti * 16 + col) * 72 + koff];
#pragma unroll
      for (int dj = 0; dj < 2; ++dj) acc[ti][dj] = MFMA16(aq, bp[dj], acc[ti][dj]);
    }
  }
  // S @ V (skip K-steps entirely above the diagonal)
#pragma unroll
  for (int s = 0; s < 2; ++s) {
    const int koff = s * 32 + quad * 8;
    shortx8 bv[2];
#pragma unroll
    for (int dj = 0; dj < 2; ++dj)
      bv[dj] = lds8(&Vt[((wave * 2 + dj) * 16 + col) * 68 + koff]);
    for (int ti = (s == 0 ? 0 : 2); ti < 4; ++ti) {
      shortx8 as = *(const shortx8*)&Ss[(ti * 16 + col) * 72 + koff];
#pragma unroll
      for (int dj = 0; dj < 2; ++dj) acc[ti][dj] = MFMA16(as, bv[dj], acc[ti][dj]);
    }
  }

  // ---- epilogue: bounce O through LDS, then coalesced dwordx4 stores ----
  __syncthreads();   // B3: all smem reads done before aliasing
  float* Ob = (float*)smem;                  // [t][d] 64 x 132 fp32 (33,792 B)
#pragma unroll
  for (int ti = 0; ti < 4; ++ti)
#pragma unroll
    for (int dj = 0; dj < 2; ++dj)
#pragma unroll
      for (int r = 0; r < 4; ++r) {
        int t = ti * 16 + quad * 4 + r;
        int d = (wave * 2 + dj) * 16 + col;
        Ob[t * 132 + d] = acc[ti][dj][r];    // <=2-way banked
      }
  __syncthreads();   // B4: Ob complete
#pragma unroll
  for (int it = 0; it < 8; ++it) {
    int j = tid + it * 256;
    int t = j >> 5, dq = j & 31;
    float4v o = *(const float4v*)&Ob[t * 132 + dq * 4];
    *(float4v*)(obase + (size_t)t * 1024 + dq * 4) = o;   // 1 KB/wave/instr
  }
}

// ---------------------------------------------------------------------------
extern "C" void kernel_launch(void* const* d_in, const int* in_sizes, int n_in,
                              void* d_out, int out_size, void* d_ws, size_t ws_size,
                              hipStream_t stream) {
  (void)in_sizes; (void)n_in; (void)out_size; (void)ws_size;
  const float* Q     = (const float*)d_in[0];
  const float* V     = (const float*)d_in[1];
  const float* state = (const float*)d_in[2];
  float* out        = (float*)d_out;
  float* new_state  = out + (size_t)4 * 2048 * 8 * 128;
  unsigned int* ws1 = (unsigned int*)d_ws;                 // 16.8 MB bf16 (permuted)
  unsigned int* ws2 = ws1 + (size_t)32 * 131072;           // 16.8 MB bf16 (permuted)

  k_phase1<<<1024, 256, 0, stream>>>(Q, V, ws1);
  k_prefix<<<512, 256, 0, stream>>>(state, ws1, ws2, new_state);
  k_phase2<<<1024, 256, 0, stream>>>(Q, V, ws2, out);
}